// Round 11
// baseline (226.336 us; speedup 1.0000x reference)
//
#include <hip/hip_runtime.h>
#include <hip/hip_bf16.h>
#include <stdint.h>

typedef __bf16 bf16_t;
typedef __bf16 bf16x8 __attribute__((ext_vector_type(8)));
typedef float  f32x4  __attribute__((ext_vector_type(4)));

static constexpr int BB  = 64;     // batch
static constexpr int NN  = 257;    // tokens
static constexpr int CC  = 768;    // channels
static constexpr int HH  = 12;     // heads
static constexpr int M   = BB * NN;   // 16448 rows
static constexpr int NP  = 288;    // padded token count
static constexpr int KLD = 72;     // K row stride (144B == 4 mod 32 dw: balanced)
static constexpr int VLD = 328;    // V^T row stride (656B == 4 mod 32 dw: balanced)
static constexpr int PLD = 296;    // P lds row stride
static constexpr int BJT = 24;     // bias jt dim padded (18 used), bf16
static constexpr float QSCALE = 0.125f;

// ---- workspace layout (bytes) ----
static constexpr size_t OFF_WQKV = 0;
static constexpr size_t SZ_WQKV  = (size_t)3 * CC * CC * 2;
static constexpr size_t OFF_WPRJ = OFF_WQKV + SZ_WQKV;
static constexpr size_t SZ_WPRJ  = (size_t)CC * CC * 2;
static constexpr size_t OFF_Q    = OFF_WPRJ + SZ_WPRJ;
static constexpr size_t SZ_Q     = (size_t)BB * HH * NP * 64 * 2;
static constexpr size_t OFF_K    = OFF_Q + SZ_Q;
static constexpr size_t SZ_K     = (size_t)BB * HH * NP * KLD * 2;
static constexpr size_t OFF_V    = OFF_K + SZ_K;
static constexpr size_t SZ_V     = (size_t)BB * HH * 64 * VLD * 2;
static constexpr size_t OFF_BIAS = OFF_V + SZ_V;
static constexpr size_t SZ_BIAS  = (size_t)HH * NP * 16 * BJT * 2;   // bf16
static constexpr size_t OFF_AO   = OFF_BIAS + SZ_BIAS;
static constexpr size_t SZ_AO    = (size_t)M * CC * 2;

__device__ __forceinline__ void load_lds16(const bf16_t* g, bf16_t* l) {
  __builtin_amdgcn_global_load_lds(
      (const __attribute__((address_space(1))) uint32_t*)g,
      (__attribute__((address_space(3))) uint32_t*)l, 16, 0, 0);
}

// -- prep: weight converts (vectorized) + bias gather + vec pad zero --
// (x -> bf16 conversion now fused into the QKV GEMM's A staging, T14-style)
__global__ void prep_kernel(const float* __restrict__ qkv_w,
                            const float* __restrict__ proj_w,
                            const float* __restrict__ rpb,
                            const int* __restrict__ rpi,
                            bf16_t* __restrict__ wqkv, bf16_t* __restrict__ wprj,
                            bf16_t* __restrict__ biasb,
                            bf16_t* __restrict__ kz, bf16_t* __restrict__ vz) {
  const int NW14 = 3 * CC * CC / 4;       // qkv_w cvt (float4 units)
  const int NW24 = CC * CC / 4;           // proj_w cvt
  const int NBI  = HH * NP * 16 * BJT;    // bias gather (scalar units)
  const int NPK2 = BB * HH * 279;         // K pad: 279 x 16B chunks per bh
  const int NPV2 = BB * HH * 64 * 9;      // V pad: 9 x 16B chunks per row
  const int total = NW14 + NW24 + NBI + NPK2 + NPV2;
  const uint4 zz = {0u, 0u, 0u, 0u};
  for (int u = blockIdx.x * blockDim.x + threadIdx.x; u < total;
       u += gridDim.x * blockDim.x) {
    if (u < NW14) {
      float4 v = ((const float4*)qkv_w)[u];
      union { ushort4 us; bf16_t b[4]; } cv;
      cv.b[0] = (bf16_t)v.x; cv.b[1] = (bf16_t)v.y;
      cv.b[2] = (bf16_t)v.z; cv.b[3] = (bf16_t)v.w;
      ((ushort4*)wqkv)[u] = cv.us;
    } else if (u < NW14 + NW24) {
      int t = u - NW14;
      float4 v = ((const float4*)proj_w)[t];
      union { ushort4 us; bf16_t b[4]; } cv;
      cv.b[0] = (bf16_t)v.x; cv.b[1] = (bf16_t)v.y;
      cv.b[2] = (bf16_t)v.z; cv.b[3] = (bf16_t)v.w;
      ((ushort4*)wprj)[t] = cv.us;
    } else if (u < NW14 + NW24 + NBI) {
      int t  = u - NW14 - NW24;
      int jt = t % BJT;
      int c  = (t / BJT) & 15;
      int q  = (t / (BJT * 16)) % NP;
      int h  = t / (BJT * 16 * NP);
      int key = jt * 16 + c;
      float val;
      if (jt >= 18)                val = 0.0f;        // pad, never read
      else if (key < NN && q < NN) val = rpb[rpi[q * NN + key] * HH + h];
      else                         val = (key >= NN) ? -1e30f : 0.0f;
      biasb[t] = (bf16_t)val;
    } else if (u < NW14 + NW24 + NBI + NPK2) {
      int t = u - NW14 - NW24 - NBI;
      int bh = t / 279, c = t - bh * 279;
      // K pad rows 257..287: contiguous 4464B per bh, 16B-aligned
      *(uint4*)(kz + (size_t)bh * NP * KLD + 257 * KLD + c * 8) = zz;
    } else {
      int t = u - NW14 - NW24 - NBI - NPK2;
      int row = t / 9, c = t - row * 9;
      // V pad elems 256..327 per row (col 256 is rewritten by GEMM after)
      *(uint4*)(vz + (size_t)row * VLD + 256 + c * 8) = zz;
    }
  }
}

// ---- 128x256 GEMM (8 waves), m97 2-barrier loop, zero-conflict swizzle ----
// C[m][n] = sum_k A[m][k]*Bt[n][k].
// MODE 0: A = x (f32); conversion fused via T14 issue-early/write-late split:
//   f32 prefetch for kt+1 issued at bottom of kt (drains inside sync2's
//   existing vmcnt(0)); at top of kt+1 A-staging is reg->cvt->ds_write only.
//   LDS mapping byte-identical to global_load_lds staging.
//   QKV scatter epilogue: tn 0-2 = Q, 3-5 = K, 6-8 = V.
// MODE 1: A = ao (bf16) via global_load_lds; proj epilogue.
template <int MODE, int GN>
__global__ __launch_bounds__(512) void gemm_kernel(
    const void* __restrict__ Ain, const bf16_t* __restrict__ Bt,
    const float* __restrict__ bias0, const float* __restrict__ bias1,
    bf16_t* __restrict__ qo, bf16_t* __restrict__ ko, bf16_t* __restrict__ vo,
    float* __restrict__ fo) {
  __shared__ bf16_t smem[24576];           // A 8192 | B 16384  (48 KiB)
  bf16_t* Alds = smem;
  bf16_t* Blds = smem + 8192;

  // bijective XCD swizzle (m204 variant)
  const int nwg = gridDim.x, orig = blockIdx.x;
  const int qq = nwg >> 3, rr8 = nwg & 7;
  const int xcd = orig & 7, local = orig >> 3;
  const int wg = (xcd < rr8 ? xcd * (qq + 1) : rr8 * (qq + 1) + (xcd - rr8) * qq) + local;
  const int tm = wg / GN, tn = wg % GN;

  const int tid = threadIdx.x;
  const int w = tid >> 6, lane = tid & 63;
  const int wm = w >> 2, wn = w & 3;       // wave tile 64x64 within 128x256
  const int g = lane >> 4, cq = lane & 15;
  const int c7 = cq & 7;
  const int lr8 = lane >> 3;                           // 0..7 row within chunk
  const int stgc = ((lane & 7) ^ (lane >> 3)) << 3;    // inverse-swizzled src col
  f32x4 acc[4][4] = {};

  // A row addresses (MODE 0): fixed per thread across kt
  int arow0 = tm * 128 + 0 * 64 + w * 8 + lr8;  arow0 = arow0 < M ? arow0 : M - 1;
  int arow1 = tm * 128 + 1 * 64 + w * 8 + lr8;  arow1 = arow1 < M ? arow1 : M - 1;

  f32x4 pa00, pa01, pa10, pa11;   // A f32 prefetch regs (MODE 0)
  if (MODE == 0) {
    const float* Axf = (const float*)Ain;
    const f32x4* s0 = (const f32x4*)(Axf + (size_t)arow0 * CC + 0 + stgc);
    const f32x4* s1 = (const f32x4*)(Axf + (size_t)arow1 * CC + 0 + stgc);
    pa00 = s0[0]; pa01 = s0[1];
    pa10 = s1[0]; pa11 = s1[1];
  }

  for (int kt = 0; kt < 12; ++kt) {
    __syncthreads();
    // stage B (256x64): 4 chunks/thread, async DMA
#pragma unroll
    for (int j = 0; j < 4; ++j) {
      int r = j * 64 + w * 8 + lr8;
      int brow = tn * 256 + r;
      load_lds16(Bt + (size_t)brow * CC + kt * 64 + stgc, &Blds[(j * 64 + w * 8) * 64]);
    }
    // stage A (128x64)
    if (MODE == 0) {
      // cvt prefetched f32 -> bf16, write (byte-identical mapping to DMA path)
      bf16x8 pk0, pk1;
      pk0[0] = (bf16_t)pa00[0]; pk0[1] = (bf16_t)pa00[1];
      pk0[2] = (bf16_t)pa00[2]; pk0[3] = (bf16_t)pa00[3];
      pk0[4] = (bf16_t)pa01[0]; pk0[5] = (bf16_t)pa01[1];
      pk0[6] = (bf16_t)pa01[2]; pk0[7] = (bf16_t)pa01[3];
      pk1[0] = (bf16_t)pa10[0]; pk1[1] = (bf16_t)pa10[1];
      pk1[2] = (bf16_t)pa10[2]; pk1[3] = (bf16_t)pa10[3];
      pk1[4] = (bf16_t)pa11[0]; pk1[5] = (bf16_t)pa11[1];
      pk1[6] = (bf16_t)pa11[2]; pk1[7] = (bf16_t)pa11[3];
      *(bf16x8*)&Alds[(0 * 64 + w * 8) * 64 + lane * 8] = pk0;
      *(bf16x8*)&Alds[(1 * 64 + w * 8) * 64 + lane * 8] = pk1;
      // issue next K-tile's f32 loads (latency drains in sync2's vmcnt(0))
      if (kt < 11) {
        const float* Axf = (const float*)Ain;
        const f32x4* s0 = (const f32x4*)(Axf + (size_t)arow0 * CC + (kt + 1) * 64 + stgc);
        const f32x4* s1 = (const f32x4*)(Axf + (size_t)arow1 * CC + (kt + 1) * 64 + stgc);
        pa00 = s0[0]; pa01 = s0[1];
        pa10 = s1[0]; pa11 = s1[1];
      }
    } else {
#pragma unroll
      for (int j = 0; j < 2; ++j) {
        int r = j * 64 + w * 8 + lr8;
        int arow = tm * 128 + r;
        arow = (arow < M) ? arow : (M - 1);
        load_lds16((const bf16_t*)Ain + (size_t)arow * CC + kt * 64 + stgc,
                   &Alds[(j * 64 + w * 8) * 64]);
      }
    }
    __syncthreads();
#pragma unroll
    for (int ks = 0; ks < 2; ++ks) {
      bf16x8 af[4], bfr[4];
#pragma unroll
      for (int mi = 0; mi < 4; ++mi)
        af[mi] = *(const bf16x8*)&Alds[(wm * 64 + mi * 16 + cq) * 64 +
                                       ((((ks << 2) | g) ^ c7) << 3)];
#pragma unroll
      for (int ni = 0; ni < 4; ++ni)
        bfr[ni] = *(const bf16x8*)&Blds[(wn * 64 + ni * 16 + cq) * 64 +
                                        ((((ks << 2) | g) ^ c7) << 3)];
#pragma unroll
      for (int mi = 0; mi < 4; ++mi)
#pragma unroll
        for (int ni = 0; ni < 4; ++ni)
          acc[mi][ni] = __builtin_amdgcn_mfma_f32_16x16x32_bf16(
              af[mi], bfr[ni], acc[mi][ni], 0, 0, 0);
    }
  }

  if (MODE == 0 && tn >= 6) {
    // ---- V blocks: transpose epilogue via per-wave LDS scratch ----
    __syncthreads();                       // all main-loop ds_reads complete
    bf16_t* scr = &smem[w * 2048];         // 64*21 = 1344 elems used per wave
    const int tokBase = tm * 128 + wm * 64;
    const int m2 = tokBase + lane;         // this lane's token (read phase)
    const bool mok = m2 < M;
    const int b2 = mok ? m2 / NN : 0;
    const int nn2 = mok ? (m2 - b2 * NN) : 0;
    const int cbase = (tn - 6) * 256 + wn * 64;
#pragma unroll
    for (int ni = 0; ni < 4; ++ni) {
      // write phase: lane (g,cq) holds tok=mi*16+4g+r, chan=cq
      float bsum = bias1[cbase + ni * 16 + cq];
#pragma unroll
      for (int mi = 0; mi < 4; ++mi)
#pragma unroll
        for (int r = 0; r < 4; ++r)
          scr[(mi * 16 + 4 * g + r) * 21 + cq] = (bf16_t)(acc[mi][ni][r] + bsum);
      asm volatile("s_waitcnt lgkmcnt(0)" ::: "memory");
      __builtin_amdgcn_sched_barrier(0);
      // read phase: lane = token, loop channels; contiguous 128B runs per row
      if (mok) {
#pragma unroll
        for (int ch = 0; ch < 16; ++ch) {
          bf16_t v = scr[lane * 21 + ch];
          int c2 = cbase + ni * 16 + ch;
          int h = c2 >> 6, hd = c2 & 63;
          vo[((size_t)(b2 * HH + h) * 64 + hd) * VLD + nn2] = v;
        }
      }
      asm volatile("s_waitcnt lgkmcnt(0)" ::: "memory");
      __builtin_amdgcn_sched_barrier(0);
    }
  } else {
#pragma unroll
    for (int mi = 0; mi < 4; ++mi) {
#pragma unroll
      for (int r = 0; r < 4; ++r) {
        int m = tm * 128 + wm * 64 + mi * 16 + 4 * g + r;
        if (m >= M) continue;
        int bidx = m / NN, nn = m % NN;
#pragma unroll
        for (int ni = 0; ni < 4; ++ni) {
          int cg = tn * 256 + wn * 64 + ni * 16 + cq;
          float v = acc[mi][ni][r];
          if (MODE == 0) {
            if (cg < CC) {                       // Q (+bias, *scale)
              int h = cg >> 6, hd = cg & 63;
              qo[((size_t)(bidx * HH + h) * NP + nn) * 64 + hd] =
                  (bf16_t)((v + bias0[cg]) * QSCALE);
            } else {                             // K (tn 3..5 only here)
              int c2 = cg - CC; int h = c2 >> 6, hd = c2 & 63;
              ko[((size_t)(bidx * HH + h) * NP + nn) * KLD + hd] = (bf16_t)v;
            }
          } else {
            fo[(size_t)m * CC + cg] = v + bias0[cg];
          }
        }
      }
    }
  }
}

// ------ attention: one block per (b,h), 8 waves, K/V staged in LDS ------
// LDS: K 20992 elems ([288][72] + pad) | V 20992 ([64][328]) | P 8x[16][296]
__global__ __launch_bounds__(512, 1) void attn_kernel(
    const bf16_t* __restrict__ qg, const bf16_t* __restrict__ kg,
    const bf16_t* __restrict__ vg, const bf16_t* __restrict__ biasb,
    bf16_t* __restrict__ outb) {
  __shared__ bf16_t shm[79872];
  const int bh = blockIdx.x;
  const int b = bh / HH, h = bh % HH;
  const int w = threadIdx.x >> 6, lane = threadIdx.x & 63;
  const int g = lane >> 4, cq = lane & 15;
  const bf16_t* qp = qg + (size_t)bh * NP * 64;
  const bf16_t* kp = kg + (size_t)bh * NP * KLD;
  const bf16_t* vp = vg + (size_t)bh * 64 * VLD;
  const bf16_t* bp = biasb + (size_t)h * NP * 16 * BJT;
  bf16_t* Klds = shm;            // 20992 elems
  bf16_t* Vlds = shm + 20992;    // 20992 elems
  bf16_t* pl   = shm + 41984 + w * (16 * PLD);

  // ---- stage K (41984B incl tail-pad) + V (41984B): 82 chunks of 1KB
  for (int i = w; i < 82; i += 8) {
    if (i < 41) load_lds16(kp + i * 512 + lane * 8, Klds + i * 512);
    else        load_lds16(vp + (i - 41) * 512 + lane * 8, Vlds + (i - 41) * 512);
  }
  asm volatile("s_waitcnt vmcnt(0)" ::: "memory");
  __syncthreads();

  for (int qt = w; qt < 17; qt += 8) {
    bf16x8 aq0 = *(const bf16x8*)&qp[(qt * 16 + cq) * 64 + 8 * g];
    bf16x8 aq1 = *(const bf16x8*)&qp[(qt * 16 + cq) * 64 + 32 + 8 * g];

    // init S with rel-pos bias (bf16 table, L2-resident)
    f32x4 s[18];
#pragma unroll
    for (int r = 0; r < 4; ++r) {
      const bf16_t* bb = &bp[((qt * 16 + 4 * g + r) * 16 + cq) * BJT];
      bf16x8 b0 = *(const bf16x8*)(bb);
      bf16x8 b1 = *(const bf16x8*)(bb + 8);
      bf16x8 b2 = *(const bf16x8*)(bb + 16);
#pragma unroll
      for (int jt = 0; jt < 8; ++jt)  s[jt][r] = (float)b0[jt];
#pragma unroll
      for (int jt = 8; jt < 16; ++jt) s[jt][r] = (float)b1[jt - 8];
      s[16][r] = (float)b2[0];
      s[17][r] = (float)b2[1];
    }

    // S += Q K^T  (K from LDS)
#pragma unroll
    for (int jt = 0; jt < 18; ++jt) {
      bf16x8 kb0 = *(const bf16x8*)&Klds[(jt * 16 + cq) * KLD + 8 * g];
      bf16x8 kb1 = *(const bf16x8*)&Klds[(jt * 16 + cq) * KLD + 32 + 8 * g];
      s[jt] = __builtin_amdgcn_mfma_f32_16x16x32_bf16(aq0, kb0, s[jt], 0, 0, 0);
      s[jt] = __builtin_amdgcn_mfma_f32_16x16x32_bf16(aq1, kb1, s[jt], 0, 0, 0);
    }

    float inv[4];
#pragma unroll
    for (int r = 0; r < 4; ++r) {
      float mx = s[0][r];
#pragma unroll
      for (int jt = 1; jt < 18; ++jt) mx = fmaxf(mx, s[jt][r]);
      mx = fmaxf(mx, __shfl_xor(mx, 1, 16));
      mx = fmaxf(mx, __shfl_xor(mx, 2, 16));
      mx = fmaxf(mx, __shfl_xor(mx, 4, 16));
      mx = fmaxf(mx, __shfl_xor(mx, 8, 16));
      float sum = 0.f;
#pragma unroll
      for (int jt = 0; jt < 18; ++jt) {
        float e = __expf(s[jt][r] - mx);
        s[jt][r] = e;
        sum += e;
      }
      sum += __shfl_xor(sum, 1, 16);
      sum += __shfl_xor(sum, 2, 16);
      sum += __shfl_xor(sum, 4, 16);
      sum += __shfl_xor(sum, 8, 16);
      inv[r] = 1.0f / sum;
    }

#pragma unroll
    for (int jt = 0; jt < 18; ++jt)
#pragma unroll
      for (int r = 0; r < 4; ++r)
        pl[(4 * g + r) * PLD + jt * 16 + cq] = (bf16_t)s[jt][r];
    __asm__ volatile("s_waitcnt lgkmcnt(0)" ::: "memory");
    __builtin_amdgcn_sched_barrier(0);

    // O = P V  (V^T from LDS)
    f32x4 o[4] = {};
#pragma unroll
    for (int kk = 0; kk < 9; ++kk) {
      bf16x8 pa = *(const bf16x8*)&pl[cq * PLD + kk * 32 + 8 * g];
#pragma unroll
      for (int nt = 0; nt < 4; ++nt) {
        bf16x8 vb = *(const bf16x8*)&Vlds[(nt * 16 + cq) * VLD + kk * 32 + 8 * g];
        o[nt] = __builtin_amdgcn_mfma_f32_16x16x32_bf16(pa, vb, o[nt], 0, 0, 0);
      }
    }

#pragma unroll
    for (int r = 0; r < 4; ++r) {
      int q = qt * 16 + 4 * g + r;
      if (q < NN) {
        float iv = inv[r];
#pragma unroll
        for (int nt = 0; nt < 4; ++nt)
          outb[((size_t)b * NN + q) * CC + h * 64 + nt * 16 + cq] =
              (bf16_t)(o[nt][r] * iv);
      }
    }
  }
}

// -------------------- launch --------------------
extern "C" void kernel_launch(void* const* d_in, const int* in_sizes, int n_in,
                              void* d_out, int out_size, void* d_ws, size_t ws_size,
                              hipStream_t stream) {
  const float* x      = (const float*)d_in[0];
  const float* qkv_w  = (const float*)d_in[1];
  const float* q_bias = (const float*)d_in[2];
  const float* v_bias = (const float*)d_in[3];
  const float* rpb    = (const float*)d_in[4];
  const float* proj_w = (const float*)d_in[5];
  const float* proj_b = (const float*)d_in[6];
  const int*   rpi    = (const int*)d_in[7];

  char* ws = (char*)d_ws;
  bf16_t* wqkv  = (bf16_t*)(ws + OFF_WQKV);
  bf16_t* wprj  = (bf16_t*)(ws + OFF_WPRJ);
  bf16_t* qo    = (bf16_t*)(ws + OFF_Q);
  bf16_t* ko    = (bf16_t*)(ws + OFF_K);
  bf16_t* vo    = (bf16_t*)(ws + OFF_V);
  bf16_t* biasb = (bf16_t*)(ws + OFF_BIAS);
  bf16_t* ao    = (bf16_t*)(ws + OFF_AO);
  float*  out   = (float*)d_out;

  prep_kernel<<<2048, 256, 0, stream>>>(qkv_w, proj_w, rpb, rpi,
                                        wqkv, wprj, biasb, ko, vo);
  gemm_kernel<0, 9><<<129 * 9, 512, 0, stream>>>((const void*)x, wqkv,
                                                 q_bias, v_bias,
                                                 qo, ko, vo, nullptr);
  attn_kernel<<<768, 512, 0, stream>>>(qo, ko, vo, biasb, ao);
  gemm_kernel<1, 3><<<129 * 3, 512, 0, stream>>>((const void*)ao, wprj,
                                                 proj_b, nullptr,
                                                 nullptr, nullptr, nullptr, out);
}

// Round 12
// 182.522 us; speedup vs baseline: 1.2400x; 1.2400x over previous
//
#include <hip/hip_runtime.h>
#include <hip/hip_bf16.h>
#include <stdint.h>

typedef __bf16 bf16_t;
typedef __bf16 bf16x8 __attribute__((ext_vector_type(8)));
typedef float  f32x4  __attribute__((ext_vector_type(4)));

static constexpr int BB  = 64;     // batch
static constexpr int NN  = 257;    // tokens
static constexpr int CC  = 768;    // channels
static constexpr int HH  = 12;     // heads
static constexpr int M   = BB * NN;   // 16448 rows
static constexpr int NP  = 288;    // padded token count
static constexpr int KLD = 72;     // K row stride (144B == 4 mod 32 dw: balanced)
static constexpr int VLD = 328;    // V^T row stride (656B == 4 mod 32 dw: balanced)
static constexpr int PLD = 296;    // P lds row stride
static constexpr int BJT = 24;     // bias jt dim padded (18 used), bf16
static constexpr float QSCALE = 0.125f;

// ---- workspace layout (bytes) ----
static constexpr size_t OFF_WQKV = 0;
static constexpr size_t SZ_WQKV  = (size_t)3 * CC * CC * 2;
static constexpr size_t OFF_WPRJ = OFF_WQKV + SZ_WQKV;
static constexpr size_t SZ_WPRJ  = (size_t)CC * CC * 2;
static constexpr size_t OFF_Q    = OFF_WPRJ + SZ_WPRJ;
static constexpr size_t SZ_Q     = (size_t)BB * HH * NP * 64 * 2;
static constexpr size_t OFF_K    = OFF_Q + SZ_Q;
static constexpr size_t SZ_K     = (size_t)BB * HH * NP * KLD * 2;
static constexpr size_t OFF_V    = OFF_K + SZ_K;
static constexpr size_t SZ_V     = (size_t)BB * HH * 64 * VLD * 2;
static constexpr size_t OFF_BIAS = OFF_V + SZ_V;
static constexpr size_t SZ_BIAS  = (size_t)HH * NP * 16 * BJT * 2;   // bf16
static constexpr size_t OFF_AO   = OFF_BIAS + SZ_BIAS;
static constexpr size_t SZ_AO    = (size_t)M * CC * 2;

__device__ __forceinline__ void load_lds16(const bf16_t* g, bf16_t* l) {
  __builtin_amdgcn_global_load_lds(
      (const __attribute__((address_space(1))) uint32_t*)g,
      (__attribute__((address_space(3))) uint32_t*)l, 16, 0, 0);
}

// -- prep: weight converts (vectorized) + bias gather + vec pad zero --
// (x -> bf16 conversion fused into the QKV GEMM's A staging)
__global__ void prep_kernel(const float* __restrict__ qkv_w,
                            const float* __restrict__ proj_w,
                            const float* __restrict__ rpb,
                            const int* __restrict__ rpi,
                            bf16_t* __restrict__ wqkv, bf16_t* __restrict__ wprj,
                            bf16_t* __restrict__ biasb,
                            bf16_t* __restrict__ kz, bf16_t* __restrict__ vz) {
  const int NW14 = 3 * CC * CC / 4;       // qkv_w cvt (float4 units)
  const int NW24 = CC * CC / 4;           // proj_w cvt
  const int NBI  = HH * NP * 16 * BJT;    // bias gather (scalar units)
  const int NPK2 = BB * HH * 279;         // K pad: 279 x 16B chunks per bh
  const int NPV2 = BB * HH * 64 * 9;      // V pad: 9 x 16B chunks per row
  const int total = NW14 + NW24 + NBI + NPK2 + NPV2;
  const uint4 zz = {0u, 0u, 0u, 0u};
  for (int u = blockIdx.x * blockDim.x + threadIdx.x; u < total;
       u += gridDim.x * blockDim.x) {
    if (u < NW14) {
      float4 v = ((const float4*)qkv_w)[u];
      union { ushort4 us; bf16_t b[4]; } cv;
      cv.b[0] = (bf16_t)v.x; cv.b[1] = (bf16_t)v.y;
      cv.b[2] = (bf16_t)v.z; cv.b[3] = (bf16_t)v.w;
      ((ushort4*)wqkv)[u] = cv.us;
    } else if (u < NW14 + NW24) {
      int t = u - NW14;
      float4 v = ((const float4*)proj_w)[t];
      union { ushort4 us; bf16_t b[4]; } cv;
      cv.b[0] = (bf16_t)v.x; cv.b[1] = (bf16_t)v.y;
      cv.b[2] = (bf16_t)v.z; cv.b[3] = (bf16_t)v.w;
      ((ushort4*)wprj)[t] = cv.us;
    } else if (u < NW14 + NW24 + NBI) {
      int t  = u - NW14 - NW24;
      int jt = t % BJT;
      int c  = (t / BJT) & 15;
      int q  = (t / (BJT * 16)) % NP;
      int h  = t / (BJT * 16 * NP);
      int key = jt * 16 + c;
      float val;
      if (jt >= 18)                val = 0.0f;        // pad, never read
      else if (key < NN && q < NN) val = rpb[rpi[q * NN + key] * HH + h];
      else                         val = (key >= NN) ? -1e30f : 0.0f;
      biasb[t] = (bf16_t)val;
    } else if (u < NW14 + NW24 + NBI + NPK2) {
      int t = u - NW14 - NW24 - NBI;
      int bh = t / 279, c = t - bh * 279;
      // K pad rows 257..287: contiguous 4464B per bh, 16B-aligned
      *(uint4*)(kz + (size_t)bh * NP * KLD + 257 * KLD + c * 8) = zz;
    } else {
      int t = u - NW14 - NW24 - NBI - NPK2;
      int row = t / 9, c = t - row * 9;
      // V pad elems 256..327 per row (col 256 is rewritten by GEMM after)
      *(uint4*)(vz + (size_t)row * VLD + 256 + c * 8) = zz;
    }
  }
}

// ---- 128x256 GEMM (8 waves), m97 2-barrier loop, zero-conflict swizzle ----
// C[m][n] = sum_k A[m][k]*Bt[n][k].
// MODE 0: A = x (f32), cvt fused into staging.  ORDER MATTERS (r9 lesson):
//   A f32 loads issue FIRST, then B's global_load_lds.  vmcnt is ordered, so
//   the compiler's wait before the cvt is vmcnt(4) -- B's DMA stays in flight
//   and drains at sync2 as designed.  (r9 issued B first -> waiting for A
//   forced vmcnt(0), serializing B's DMA every iteration -> 121us.)
//   QKV scatter epilogue: tn 0-2 = Q, 3-5 = K, 6-8 = V.
// MODE 1: A = ao (bf16) via global_load_lds; proj epilogue.
template <int MODE, int GN>
__global__ __launch_bounds__(512) void gemm_kernel(
    const void* __restrict__ Ain, const bf16_t* __restrict__ Bt,
    const float* __restrict__ bias0, const float* __restrict__ bias1,
    bf16_t* __restrict__ qo, bf16_t* __restrict__ ko, bf16_t* __restrict__ vo,
    float* __restrict__ fo) {
  __shared__ bf16_t smem[24576];           // A 8192 | B 16384  (48 KiB)
  bf16_t* Alds = smem;
  bf16_t* Blds = smem + 8192;

  // bijective XCD swizzle (m204 variant)
  const int nwg = gridDim.x, orig = blockIdx.x;
  const int qq = nwg >> 3, rr8 = nwg & 7;
  const int xcd = orig & 7, local = orig >> 3;
  const int wg = (xcd < rr8 ? xcd * (qq + 1) : rr8 * (qq + 1) + (xcd - rr8) * qq) + local;
  const int tm = wg / GN, tn = wg % GN;

  const int tid = threadIdx.x;
  const int w = tid >> 6, lane = tid & 63;
  const int wm = w >> 2, wn = w & 3;       // wave tile 64x64 within 128x256
  const int g = lane >> 4, cq = lane & 15;
  const int c7 = cq & 7;
  const int lr8 = lane >> 3;                           // 0..7 row within chunk
  const int stgc = ((lane & 7) ^ (lane >> 3)) << 3;    // inverse-swizzled src col
  f32x4 acc[4][4] = {};

  // A row addresses (MODE 0): fixed per thread across kt
  int arow0 = tm * 128 + 0 * 64 + w * 8 + lr8;  arow0 = arow0 < M ? arow0 : M - 1;
  int arow1 = tm * 128 + 1 * 64 + w * 8 + lr8;  arow1 = arow1 < M ? arow1 : M - 1;

  for (int kt = 0; kt < 12; ++kt) {
    __syncthreads();
    if (MODE == 0) {
      // A f32 loads FIRST (oldest in vmcnt order)
      const float* Axf = (const float*)Ain;
      const f32x4* s0 = (const f32x4*)(Axf + (size_t)arow0 * CC + kt * 64 + stgc);
      const f32x4* s1 = (const f32x4*)(Axf + (size_t)arow1 * CC + kt * 64 + stgc);
      f32x4 pa00 = s0[0], pa01 = s0[1];
      f32x4 pa10 = s1[0], pa11 = s1[1];
      // B DMA issues while A loads are in flight
#pragma unroll
      for (int j = 0; j < 4; ++j) {
        int r = j * 64 + w * 8 + lr8;
        int brow = tn * 256 + r;
        load_lds16(Bt + (size_t)brow * CC + kt * 64 + stgc, &Blds[(j * 64 + w * 8) * 64]);
      }
      // cvt + write A: compiler waits vmcnt(4) here (A done, B still in flight)
      bf16x8 pk0, pk1;
      pk0[0] = (bf16_t)pa00[0]; pk0[1] = (bf16_t)pa00[1];
      pk0[2] = (bf16_t)pa00[2]; pk0[3] = (bf16_t)pa00[3];
      pk0[4] = (bf16_t)pa01[0]; pk0[5] = (bf16_t)pa01[1];
      pk0[6] = (bf16_t)pa01[2]; pk0[7] = (bf16_t)pa01[3];
      pk1[0] = (bf16_t)pa10[0]; pk1[1] = (bf16_t)pa10[1];
      pk1[2] = (bf16_t)pa10[2]; pk1[3] = (bf16_t)pa10[3];
      pk1[4] = (bf16_t)pa11[0]; pk1[5] = (bf16_t)pa11[1];
      pk1[6] = (bf16_t)pa11[2]; pk1[7] = (bf16_t)pa11[3];
      *(bf16x8*)&Alds[(0 * 64 + w * 8) * 64 + lane * 8] = pk0;
      *(bf16x8*)&Alds[(1 * 64 + w * 8) * 64 + lane * 8] = pk1;
    } else {
#pragma unroll
      for (int j = 0; j < 2; ++j) {
        int r = j * 64 + w * 8 + lr8;
        int arow = tm * 128 + r;
        arow = (arow < M) ? arow : (M - 1);
        load_lds16((const bf16_t*)Ain + (size_t)arow * CC + kt * 64 + stgc,
                   &Alds[(j * 64 + w * 8) * 64]);
      }
#pragma unroll
      for (int j = 0; j < 4; ++j) {
        int r = j * 64 + w * 8 + lr8;
        int brow = tn * 256 + r;
        load_lds16(Bt + (size_t)brow * CC + kt * 64 + stgc, &Blds[(j * 64 + w * 8) * 64]);
      }
    }
    __syncthreads();
#pragma unroll
    for (int ks = 0; ks < 2; ++ks) {
      bf16x8 af[4], bfr[4];
#pragma unroll
      for (int mi = 0; mi < 4; ++mi)
        af[mi] = *(const bf16x8*)&Alds[(wm * 64 + mi * 16 + cq) * 64 +
                                       ((((ks << 2) | g) ^ c7) << 3)];
#pragma unroll
      for (int ni = 0; ni < 4; ++ni)
        bfr[ni] = *(const bf16x8*)&Blds[(wn * 64 + ni * 16 + cq) * 64 +
                                        ((((ks << 2) | g) ^ c7) << 3)];
#pragma unroll
      for (int mi = 0; mi < 4; ++mi)
#pragma unroll
        for (int ni = 0; ni < 4; ++ni)
          acc[mi][ni] = __builtin_amdgcn_mfma_f32_16x16x32_bf16(
              af[mi], bfr[ni], acc[mi][ni], 0, 0, 0);
    }
  }

  if (MODE == 0 && tn >= 6) {
    // ---- V blocks: transpose epilogue via per-wave LDS scratch ----
    __syncthreads();                       // all main-loop ds_reads complete
    bf16_t* scr = &smem[w * 2048];         // 64*21 = 1344 elems used per wave
    const int tokBase = tm * 128 + wm * 64;
    const int m2 = tokBase + lane;         // this lane's token (read phase)
    const bool mok = m2 < M;
    const int b2 = mok ? m2 / NN : 0;
    const int nn2 = mok ? (m2 - b2 * NN) : 0;
    const int cbase = (tn - 6) * 256 + wn * 64;
#pragma unroll
    for (int ni = 0; ni < 4; ++ni) {
      // write phase: lane (g,cq) holds tok=mi*16+4g+r, chan=cq
      float bsum = bias1[cbase + ni * 16 + cq];
#pragma unroll
      for (int mi = 0; mi < 4; ++mi)
#pragma unroll
        for (int r = 0; r < 4; ++r)
          scr[(mi * 16 + 4 * g + r) * 21 + cq] = (bf16_t)(acc[mi][ni][r] + bsum);
      asm volatile("s_waitcnt lgkmcnt(0)" ::: "memory");
      __builtin_amdgcn_sched_barrier(0);
      // read phase: lane = token, loop channels; contiguous 128B runs per row
      if (mok) {
#pragma unroll
        for (int ch = 0; ch < 16; ++ch) {
          bf16_t v = scr[lane * 21 + ch];
          int c2 = cbase + ni * 16 + ch;
          int h = c2 >> 6, hd = c2 & 63;
          vo[((size_t)(b2 * HH + h) * 64 + hd) * VLD + nn2] = v;
        }
      }
      asm volatile("s_waitcnt lgkmcnt(0)" ::: "memory");
      __builtin_amdgcn_sched_barrier(0);
    }
  } else {
#pragma unroll
    for (int mi = 0; mi < 4; ++mi) {
#pragma unroll
      for (int r = 0; r < 4; ++r) {
        int m = tm * 128 + wm * 64 + mi * 16 + 4 * g + r;
        if (m >= M) continue;
        int bidx = m / NN, nn = m % NN;
#pragma unroll
        for (int ni = 0; ni < 4; ++ni) {
          int cg = tn * 256 + wn * 64 + ni * 16 + cq;
          float v = acc[mi][ni][r];
          if (MODE == 0) {
            if (cg < CC) {                       // Q (+bias, *scale)
              int h = cg >> 6, hd = cg & 63;
              qo[((size_t)(bidx * HH + h) * NP + nn) * 64 + hd] =
                  (bf16_t)((v + bias0[cg]) * QSCALE);
            } else {                             // K (tn 3..5 only here)
              int c2 = cg - CC; int h = c2 >> 6, hd = c2 & 63;
              ko[((size_t)(bidx * HH + h) * NP + nn) * KLD + hd] = (bf16_t)v;
            }
          } else {
            fo[(size_t)m * CC + cg] = v + bias0[cg];
          }
        }
      }
    }
  }
}

// ------ attention: one block per (b,h), 8 waves, K/V staged in LDS ------
// LDS: K 20992 elems ([288][72] + pad) | V 20992 ([64][328]) | P 8x[16][296]
__global__ __launch_bounds__(512, 1) void attn_kernel(
    const bf16_t* __restrict__ qg, const bf16_t* __restrict__ kg,
    const bf16_t* __restrict__ vg, const bf16_t* __restrict__ biasb,
    bf16_t* __restrict__ outb) {
  __shared__ bf16_t shm[79872];
  const int bh = blockIdx.x;
  const int b = bh / HH, h = bh % HH;
  const int w = threadIdx.x >> 6, lane = threadIdx.x & 63;
  const int g = lane >> 4, cq = lane & 15;
  const bf16_t* qp = qg + (size_t)bh * NP * 64;
  const bf16_t* kp = kg + (size_t)bh * NP * KLD;
  const bf16_t* vp = vg + (size_t)bh * 64 * VLD;
  const bf16_t* bp = biasb + (size_t)h * NP * 16 * BJT;
  bf16_t* Klds = shm;            // 20992 elems
  bf16_t* Vlds = shm + 20992;    // 20992 elems
  bf16_t* pl   = shm + 41984 + w * (16 * PLD);

  // ---- stage K (41984B incl tail-pad) + V (41984B): 82 chunks of 1KB
  for (int i = w; i < 82; i += 8) {
    if (i < 41) load_lds16(kp + i * 512 + lane * 8, Klds + i * 512);
    else        load_lds16(vp + (i - 41) * 512 + lane * 8, Vlds + (i - 41) * 512);
  }
  asm volatile("s_waitcnt vmcnt(0)" ::: "memory");
  __syncthreads();

  for (int qt = w; qt < 17; qt += 8) {
    bf16x8 aq0 = *(const bf16x8*)&qp[(qt * 16 + cq) * 64 + 8 * g];
    bf16x8 aq1 = *(const bf16x8*)&qp[(qt * 16 + cq) * 64 + 32 + 8 * g];

    // init S with rel-pos bias (bf16 table, L2-resident)
    f32x4 s[18];
#pragma unroll
    for (int r = 0; r < 4; ++r) {
      const bf16_t* bb = &bp[((qt * 16 + 4 * g + r) * 16 + cq) * BJT];
      bf16x8 b0 = *(const bf16x8*)(bb);
      bf16x8 b1 = *(const bf16x8*)(bb + 8);
      bf16x8 b2 = *(const bf16x8*)(bb + 16);
#pragma unroll
      for (int jt = 0; jt < 8; ++jt)  s[jt][r] = (float)b0[jt];
#pragma unroll
      for (int jt = 8; jt < 16; ++jt) s[jt][r] = (float)b1[jt - 8];
      s[16][r] = (float)b2[0];
      s[17][r] = (float)b2[1];
    }

    // S += Q K^T  (K from LDS)
#pragma unroll
    for (int jt = 0; jt < 18; ++jt) {
      bf16x8 kb0 = *(const bf16x8*)&Klds[(jt * 16 + cq) * KLD + 8 * g];
      bf16x8 kb1 = *(const bf16x8*)&Klds[(jt * 16 + cq) * KLD + 32 + 8 * g];
      s[jt] = __builtin_amdgcn_mfma_f32_16x16x32_bf16(aq0, kb0, s[jt], 0, 0, 0);
      s[jt] = __builtin_amdgcn_mfma_f32_16x16x32_bf16(aq1, kb1, s[jt], 0, 0, 0);
    }

    float inv[4];
#pragma unroll
    for (int r = 0; r < 4; ++r) {
      float mx = s[0][r];
#pragma unroll
      for (int jt = 1; jt < 18; ++jt) mx = fmaxf(mx, s[jt][r]);
      mx = fmaxf(mx, __shfl_xor(mx, 1, 16));
      mx = fmaxf(mx, __shfl_xor(mx, 2, 16));
      mx = fmaxf(mx, __shfl_xor(mx, 4, 16));
      mx = fmaxf(mx, __shfl_xor(mx, 8, 16));
      float sum = 0.f;
#pragma unroll
      for (int jt = 0; jt < 18; ++jt) {
        float e = __expf(s[jt][r] - mx);
        s[jt][r] = e;
        sum += e;
      }
      sum += __shfl_xor(sum, 1, 16);
      sum += __shfl_xor(sum, 2, 16);
      sum += __shfl_xor(sum, 4, 16);
      sum += __shfl_xor(sum, 8, 16);
      inv[r] = 1.0f / sum;
    }

#pragma unroll
    for (int jt = 0; jt < 18; ++jt)
#pragma unroll
      for (int r = 0; r < 4; ++r)
        pl[(4 * g + r) * PLD + jt * 16 + cq] = (bf16_t)s[jt][r];
    __asm__ volatile("s_waitcnt lgkmcnt(0)" ::: "memory");
    __builtin_amdgcn_sched_barrier(0);

    // O = P V  (V^T from LDS)
    f32x4 o[4] = {};
#pragma unroll
    for (int kk = 0; kk < 9; ++kk) {
      bf16x8 pa = *(const bf16x8*)&pl[cq * PLD + kk * 32 + 8 * g];
#pragma unroll
      for (int nt = 0; nt < 4; ++nt) {
        bf16x8 vb = *(const bf16x8*)&Vlds[(nt * 16 + cq) * VLD + kk * 32 + 8 * g];
        o[nt] = __builtin_amdgcn_mfma_f32_16x16x32_bf16(pa, vb, o[nt], 0, 0, 0);
      }
    }

#pragma unroll
    for (int r = 0; r < 4; ++r) {
      int q = qt * 16 + 4 * g + r;
      if (q < NN) {
        float iv = inv[r];
#pragma unroll
        for (int nt = 0; nt < 4; ++nt)
          outb[((size_t)b * NN + q) * CC + h * 64 + nt * 16 + cq] =
              (bf16_t)(o[nt][r] * iv);
      }
    }
  }
}

// -------------------- launch --------------------
extern "C" void kernel_launch(void* const* d_in, const int* in_sizes, int n_in,
                              void* d_out, int out_size, void* d_ws, size_t ws_size,
                              hipStream_t stream) {
  const float* x      = (const float*)d_in[0];
  const float* qkv_w  = (const float*)d_in[1];
  const float* q_bias = (const float*)d_in[2];
  const float* v_bias = (const float*)d_in[3];
  const float* rpb    = (const float*)d_in[4];
  const float* proj_w = (const float*)d_in[5];
  const float* proj_b = (const float*)d_in[6];
  const int*   rpi    = (const int*)d_in[7];

  char* ws = (char*)d_ws;
  bf16_t* wqkv  = (bf16_t*)(ws + OFF_WQKV);
  bf16_t* wprj  = (bf16_t*)(ws + OFF_WPRJ);
  bf16_t* qo    = (bf16_t*)(ws + OFF_Q);
  bf16_t* ko    = (bf16_t*)(ws + OFF_K);
  bf16_t* vo    = (bf16_t*)(ws + OFF_V);
  bf16_t* biasb = (bf16_t*)(ws + OFF_BIAS);
  bf16_t* ao    = (bf16_t*)(ws + OFF_AO);
  float*  out   = (float*)d_out;

  prep_kernel<<<2048, 256, 0, stream>>>(qkv_w, proj_w, rpb, rpi,
                                        wqkv, wprj, biasb, ko, vo);
  gemm_kernel<0, 9><<<129 * 9, 512, 0, stream>>>((const void*)x, wqkv,
                                                 q_bias, v_bias,
                                                 qo, ko, vo, nullptr);
  attn_kernel<<<768, 512, 0, stream>>>(qo, ko, vo, biasb, ao);
  gemm_kernel<1, 3><<<129 * 3, 512, 0, stream>>>((const void*)ao, wprj,
                                                 proj_b, nullptr,
                                                 nullptr, nullptr, nullptr, out);
}